// Round 1
// baseline (6070.515 us; speedup 1.0000x reference)
//
#include <hip/hip_runtime.h>

#define BATCH   64
#define TSTEPS  2048
#define DIN     64
#define UNITS   128
#define UNFOLDS 6

// One block per batch element. 256 threads: lane-pair (even=half0, odd=half1)
// owns one unit u = tid>>1. Recurrent W column half kept in 64 VGPRs, input
// kernel column half in 32 VGPRs. h ping-pongs through LDS; dot-product halves
// combined via shfl_xor(1). Output head fused via wave reduction.
__global__ __launch_bounds__(256) void ltc_fused_kernel(
    const float* __restrict__ x,      // [B,T,DIN]
    const float* __restrict__ kern,   // [DIN,UNITS]
    const float* __restrict__ rk,     // [UNITS,UNITS]
    const float* __restrict__ bias,   // [UNITS]
    const float* __restrict__ tau,    // [UNITS]
    const float* __restrict__ Avec,   // [UNITS]
    const float* __restrict__ okern,  // [UNITS,1]
    const float* __restrict__ obias,  // [1]
    float* __restrict__ out)          // [B,T,1]
{
    const int b    = blockIdx.x;
    const int tid  = threadIdx.x;
    const int u    = tid >> 1;   // unit owned by this lane pair
    const int half = tid & 1;    // which half of the K dimension
    const int wid  = tid >> 6;
    const int lane = tid & 63;

    __shared__ float hbuf[2][UNITS];
    __shared__ float xbuf[2][DIN];
    __shared__ float part[4];

    // --- per-thread resident weights ---
    float w[64];                 // rk[half*64 + j][u]
    #pragma unroll
    for (int j = 0; j < 64; ++j)
        w[j] = rk[(half * 64 + j) * UNITS + u];

    float kk[32];                // kern[half*32 + i][u]
    #pragma unroll
    for (int i = 0; i < 32; ++i)
        kk[i] = kern[(half * 32 + i) * UNITS + u];

    const float a_u    = Avec[u];
    const float itau   = 1.0f / tau[u];
    const float ok_u   = okern[u];
    const float bias_u = half ? 0.0f : bias[u];
    const float ob     = obias[0];
    const float dt     = 1.0f / 6.0f;

    // --- init h = 0, stage x[:,0,:] ---
    float hu = 0.0f;
    if (half == 0) hbuf[0][u] = 0.0f;
    const float* xb = x + (size_t)b * TSTEPS * DIN;
    if (tid < DIN) xbuf[0][tid] = xb[tid];
    __syncthreads();

    for (int t = 0; t < TSTEPS; ++t) {
        // prefetch next timestep's x row (latency hidden under 6 sub-steps)
        float xr = 0.0f;
        if (tid < DIN) {
            int tn = (t + 1 < TSTEPS) ? t + 1 : t;
            xr = xb[tn * DIN + tid];
        }

        // input-projection partial for this half (valid all 6 sub-steps)
        float xpacc = bias_u;
        {
            const float* xc = xbuf[t & 1];
            #pragma unroll
            for (int i = 0; i < 32; ++i)
                xpacc += xc[half * 32 + i] * kk[i];
        }

        #pragma unroll
        for (int s = 0; s < UNFOLDS; ++s) {
            // partial dot: this half of h . rk[:,u]
            float acc = xpacc;
            const float* hc = hbuf[s & 1];
            #pragma unroll
            for (int j = 0; j < 64; ++j)
                acc += hc[half * 64 + j] * w[j];

            float total = acc + __shfl_xor(acc, 1);   // combine halves
            float e = __expf(-total);
            float f = __builtin_amdgcn_rcpf(1.0f + e); // sigmoid
            float num = hu + dt * f * a_u;
            float den = 1.0f + dt * (itau + f);
            hu = num * __builtin_amdgcn_rcpf(den);

            if (half == 0) hbuf[(s & 1) ^ 1][u] = hu;  // publish new h

            if (s == UNFOLDS - 1) {
                // stash prefetched x for t+1
                if (tid < DIN) xbuf[(t + 1) & 1][tid] = xr;
                // fused output head: sum_u h[u]*okern[u]
                float q = half ? 0.0f : hu * ok_u;
                #pragma unroll
                for (int m = 1; m < 64; m <<= 1)
                    q += __shfl_xor(q, m);
                if (lane == 0) part[wid] = q;
            }
            __syncthreads();
        }

        if (tid == 0)
            out[(size_t)b * TSTEPS + t] = part[0] + part[1] + part[2] + part[3] + ob;
    }
}

extern "C" void kernel_launch(void* const* d_in, const int* in_sizes, int n_in,
                              void* d_out, int out_size, void* d_ws, size_t ws_size,
                              hipStream_t stream) {
    const float* x     = (const float*)d_in[0];
    const float* kern  = (const float*)d_in[1];
    const float* rk    = (const float*)d_in[2];
    const float* bias  = (const float*)d_in[3];
    const float* tau   = (const float*)d_in[4];
    const float* Avec  = (const float*)d_in[5];
    const float* okern = (const float*)d_in[6];
    const float* obias = (const float*)d_in[7];
    float* out = (float*)d_out;

    ltc_fused_kernel<<<BATCH, 256, 0, stream>>>(
        x, kern, rk, bias, tau, Avec, okern, obias, out);
}

// Round 2
// 4134.262 us; speedup vs baseline: 1.4683x; 1.4683x over previous
//
#include <hip/hip_runtime.h>

#define BATCH   64
#define TSTEPS  2048
#define DIN     64
#define UNITS   128
#define UNFOLDS 6
#define NTHREADS 512
#define CHUNK_STRIDE 40   // 32 data words + 8 pad: quarter q at bank offset (8q)%32

// P=4 split: thread owns unit u = tid>>2, K-quarter q = tid&3 (32 of 128 MACs).
// Quad partials combined with DPP quad_perm (VALU pipe). h ping-pongs in LDS
// with bank-padded chunk layout (conflict-free b128 broadcast reads).
// Raw s_barrier + manual lgkmcnt(0): no vmcnt drain -> x prefetch stays hidden.

__device__ __forceinline__ float quad_xor1(float v) {
    // quad_perm [1,0,3,2] = 0xB1
    return __int_as_float(__builtin_amdgcn_mov_dpp(__float_as_int(v), 0xB1, 0xF, 0xF, true));
}
__device__ __forceinline__ float quad_xor2(float v) {
    // quad_perm [2,3,0,1] = 0x4E
    return __int_as_float(__builtin_amdgcn_mov_dpp(__float_as_int(v), 0x4E, 0xF, 0xF, true));
}

__global__ __launch_bounds__(NTHREADS) void ltc_fused_kernel(
    const float* __restrict__ x,      // [B,T,DIN]
    const float* __restrict__ kern,   // [DIN,UNITS]
    const float* __restrict__ rk,     // [UNITS,UNITS]
    const float* __restrict__ bias,   // [UNITS]
    const float* __restrict__ tau,    // [UNITS]
    const float* __restrict__ Avec,   // [UNITS]
    const float* __restrict__ okern,  // [UNITS,1]
    const float* __restrict__ obias,  // [1]
    float* __restrict__ out)          // [B,T,1]
{
    const int b       = blockIdx.x;
    const int tid     = threadIdx.x;
    const int u       = tid >> 2;    // unit 0..127
    const int quarter = tid & 3;     // K-chunk 0..3
    const int wid     = tid >> 6;    // 8 waves
    const int lane    = tid & 63;

    __shared__ __align__(16) float hbuf[2][4 * CHUNK_STRIDE];
    __shared__ float part[8];

    // resident weights: this quarter's 32 rows of rk column u
    float w[32];
    #pragma unroll
    for (int m = 0; m < 32; ++m)
        w[m] = rk[(32 * quarter + m) * UNITS + u];

    // input kernel: this quarter's 16 rows of kern column u
    float kk[16];
    #pragma unroll
    for (int i = 0; i < 16; ++i)
        kk[i] = kern[(16 * quarter + i) * UNITS + u];

    const float a_u    = Avec[u];
    const float dt     = 1.0f / 6.0f;
    const float dtA    = dt * a_u;
    const float cden   = 1.0f + dt * (1.0f / tau[u]);   // 1 + dt*inv_tau
    const float ok_u   = okern[u];
    const float bias_q = (quarter == 0) ? bias[u] : 0.0f;
    const float ob     = obias[0];

    float hu = 0.0f;
    if (quarter == 0)
        hbuf[0][CHUNK_STRIDE * (u >> 5) + (u & 31)] = 0.0f;

    const float* xb = x + (size_t)b * TSTEPS * DIN;

    // stage x row t=0 into regs (this thread's quarter: 16 floats)
    float4 xr[4];
    {
        const float4* xrow = (const float4*)xb;
        #pragma unroll
        for (int m = 0; m < 4; ++m) xr[m] = xrow[4 * quarter + m];
    }

    asm volatile("s_waitcnt lgkmcnt(0)" ::: "memory");
    __builtin_amdgcn_sched_barrier(0);
    __builtin_amdgcn_s_barrier();
    __builtin_amdgcn_sched_barrier(0);

    for (int t = 0; t < TSTEPS; ++t) {
        // input-projection partial for this quarter (valid all 6 sub-steps)
        float p0 = bias_q, p1 = 0.0f;
        #pragma unroll
        for (int m = 0; m < 4; ++m) {
            p0 = fmaf(xr[m].x, kk[4 * m + 0], p0);
            p1 = fmaf(xr[m].y, kk[4 * m + 1], p1);
            p0 = fmaf(xr[m].z, kk[4 * m + 2], p0);
            p1 = fmaf(xr[m].w, kk[4 * m + 3], p1);
        }
        const float xpacc = p0 + p1;

        // prefetch next timestep's x row (no vmcnt drain at barriers -> hidden)
        float4 xn[4];
        {
            int tn = (t + 1 < TSTEPS) ? t + 1 : t;
            const float4* xrow = (const float4*)(xb + (size_t)tn * DIN);
            #pragma unroll
            for (int m = 0; m < 4; ++m) xn[m] = xrow[4 * quarter + m];
        }

        #pragma unroll
        for (int s = 0; s < UNFOLDS; ++s) {
            const float4* hq = (const float4*)&hbuf[s & 1][CHUNK_STRIDE * quarter];
            float4 h4[8];
            #pragma unroll
            for (int m = 0; m < 8; ++m) h4[m] = hq[m];

            float a0 = 0.0f, a1 = 0.0f, a2 = 0.0f, a3 = 0.0f;
            #pragma unroll
            for (int m = 0; m < 8; ++m) {
                a0 = fmaf(h4[m].x, w[4 * m + 0], a0);
                a1 = fmaf(h4[m].y, w[4 * m + 1], a1);
                a2 = fmaf(h4[m].z, w[4 * m + 2], a2);
                a3 = fmaf(h4[m].w, w[4 * m + 3], a3);
            }
            float acc = ((a0 + a1) + (a2 + a3)) + xpacc;

            // combine the 4 K-quarters within the quad (VALU DPP, no LDS)
            acc += quad_xor1(acc);
            acc += quad_xor2(acc);

            // gating + semi-implicit Euler update (replicated across quad)
            float e = __expf(-acc);
            float f = __builtin_amdgcn_rcpf(1.0f + e);
            float num = fmaf(dtA, f, hu);
            float den = fmaf(dt, f, cden);
            hu = num * __builtin_amdgcn_rcpf(den);

            if (quarter == 0)
                hbuf[(s & 1) ^ 1][CHUNK_STRIDE * (u >> 5) + (u & 31)] = hu;

            if (s == UNFOLDS - 1) {
                // fused output head: sum over quarter0 lanes of hu*ok
                float q = (quarter == 0) ? hu * ok_u : 0.0f;
                q += __shfl_xor(q, 4);
                q += __shfl_xor(q, 8);
                q += __shfl_xor(q, 16);
                q += __shfl_xor(q, 32);
                if (lane == 0) part[wid] = q;
            }

            asm volatile("s_waitcnt lgkmcnt(0)" ::: "memory");
            __builtin_amdgcn_sched_barrier(0);
            __builtin_amdgcn_s_barrier();
            __builtin_amdgcn_sched_barrier(0);
        }

        if (tid == 0) {
            float r = ob;
            #pragma unroll
            for (int k = 0; k < 8; ++k) r += part[k];
            out[(size_t)b * TSTEPS + t] = r;
        }

        #pragma unroll
        for (int m = 0; m < 4; ++m) xr[m] = xn[m];
    }
}

extern "C" void kernel_launch(void* const* d_in, const int* in_sizes, int n_in,
                              void* d_out, int out_size, void* d_ws, size_t ws_size,
                              hipStream_t stream) {
    const float* x     = (const float*)d_in[0];
    const float* kern  = (const float*)d_in[1];
    const float* rk    = (const float*)d_in[2];
    const float* bias  = (const float*)d_in[3];
    const float* tau   = (const float*)d_in[4];
    const float* Avec  = (const float*)d_in[5];
    const float* okern = (const float*)d_in[6];
    const float* obias = (const float*)d_in[7];
    float* out = (float*)d_out;

    ltc_fused_kernel<<<BATCH, NTHREADS, 0, stream>>>(
        x, kern, rk, bias, tau, Avec, okern, obias, out);
}